// Round 6
// baseline (163.993 us; speedup 1.0000x reference)
//
#include <hip/hip_runtime.h>
#include <cstddef>

// B=16, h=8, Ch=32, H=W=56, N=3136
//   heads 0-1 -> 3x3 (w3,b3), cbase hh*32
//   heads 2-4 -> 5x5 (w5,b5), cbase hh*32-64
//   heads 5-7 -> 7x7 (w7,b7), cbase hh*32-160
// out[b][n][hh*32+ch] = q[b][hh][n][ch] * dwconv(v)[b][hh][n][ch]
//
// R11: phase overlap. R5-R10 invariant: ~650 KB L1-miss bytes per CU per
// dispatch at ~13 GB/s/CU (copy sustains ~25). All prior rounds were
// BURSTY: stage burst -> __syncthreads (drains vmcnt!) -> compute with
// memory idle -> epilogue burst => ~50% duty cycle. This round overlaps:
//  - staging split: rows 0..12 written before barrier1; rows 13+ loaded
//    EARLY (in flight across the barrier) and written after conv chunk1.
//  - raw s_barrier + lgkmcnt(0) only (8-phase GEMM pattern): in-flight
//    global loads are NOT drained at the barrier.
//  - per-row conv (wave owns rows w, w+4, w+8, w+12) split into chunk1
//    (window within rows 0..12) / chunk2, with per-row q*mul->store
//    epilogue: stores spread through compute, chunk2 stage loads hide
//    under chunk1 FMAs.
// Bytes identical to R9/R10 (FETCH ~52 MB, WRITE 50176 KB) for clean
// attribution: any time delta is pure overlap.

#define BH 16
#define NH 8
#define CH 32
#define HW 56
#define NN (HW*HW)
#define ROWB (HW*CH*4)          // 7168 B per image row
#define RS 58                   // LDS row stride in px (56 + 2 gap)
#define NROWS_MAX 20            // 14 + 2*3 (K=7)
#define BUF_PX (3 + NROWS_MAX*RS + 1)   // 1164 px
#define BUF_FLOATS (BUF_PX*CH)  // 37248 floats = 148992 B

typedef float f32x4 __attribute__((ext_vector_type(4)));
typedef unsigned int u32x4 __attribute__((ext_vector_type(4)));

__device__ __forceinline__ f32x4 bload(__amdgpu_buffer_rsrc_t rs, int voff) {
    u32x4 u = __builtin_amdgcn_raw_buffer_load_b128(rs, voff, 0, 0);
    f32x4 f; __builtin_memcpy(&f, &u, 16); return f;
}

// Barrier that does NOT drain vmcnt: LDS writes fenced via lgkmcnt only,
// global loads stay in flight across it (proven 8-phase GEMM pattern).
__device__ __forceinline__ void softbar() {
    asm volatile("s_waitcnt lgkmcnt(0)" ::: "memory");
    __builtin_amdgcn_s_barrier();
    __builtin_amdgcn_sched_barrier(0);
}

// One output row: conv from LDS + q-mul + store. Staged row idx for local
// row y is s = y + dy, dy in [0, K).
template<int K>
__device__ __forceinline__ void conv_row(
    const float* __restrict__ q, float* __restrict__ out,
    f32x4 bias4, int b, int hh, int y0, int y, int cbase,
    const float* __restrict__ w_lds, const float* __restrict__ bufs,
    int x0, int ch, float mL, float mR)
{
    constexpr int P  = K / 2;
    constexpr int NR = 7 + K - 1;

    const size_t plane = ((size_t)b * NH + hh) * (size_t)NN * CH;
    const int gy = y0 + y;
    const float* qrow = q + plane + (size_t)gy * (HW * CH);

    // q prefetch issued first: latency hides under the dy-loop below.
    f32x4 qf[7];
#pragma unroll
    for (int i = 0; i < 7; ++i)
        qf[i] = *(const f32x4*)(qrow + (size_t)(x0 + i) * CH + ch);

    f32x4 acc[7];
#pragma unroll
    for (int i = 0; i < 7; ++i) acc[i] = bias4;

#pragma unroll
    for (int dy = 0; dy < K; ++dy) {
        const int s = y + dy;           // staged row idx
        const float* rb = bufs + (size_t)((3 - P + x0) + s * RS) * CH + ch;
        f32x4 r[NR];
#pragma unroll
        for (int j = 0; j < NR; ++j)
            r[j] = *(const f32x4*)(rb + j * CH);
        if constexpr (K == 7) { r[0] *= mL; r[NR - 1] *= mR; }

#pragma unroll
        for (int dx = 0; dx < K; ++dx) {
            const f32x4 w4 = *(const f32x4*)(w_lds + (dy * K + dx) * CH + ch);
#pragma unroll
            for (int i = 0; i < 7; ++i)
                acc[i] += r[i + dx] * w4;
        }
    }

    float* obase = out + ((size_t)b * NN + (size_t)gy * HW) * (NH * CH) + hh * CH + ch;
#pragma unroll
    for (int i = 0; i < 7; ++i)
        *(f32x4*)(obase + (size_t)(x0 + i) * (NH * CH)) = acc[i] * qf[i];
}

template<int K>
__device__ __forceinline__ void run_head(
    const float* __restrict__ q, const float* __restrict__ v,
    const float* __restrict__ w, const float* __restrict__ bias,
    float* __restrict__ out, int b, int hh, int y0, int cbase,
    float* __restrict__ w_lds, float* __restrict__ bufs)
{
    constexpr int P = K / 2;
    constexpr int NROWS = 14 + 2 * P;   // staged rows per block
    const int t = threadIdx.x;

    // Stage weights into LDS, layout [tap][c].
    const int nw = K * K * CH;
    for (int i = t; i < nw; i += 256) {
        int tap = i >> 5, c = i & 31;
        w_lds[tap * CH + c] = w[(cbase + c) * (K * K) + tap];
    }

    // Zero pad px: lead 3, 2-px gap after each row, 1 trailing.
    {
        f32x4 z = {0.f, 0.f, 0.f, 0.f};
        const int NG = 3 + 2 * NROWS + 1;
        for (int i = t; i < NG * 8; i += 256) {
            const int g = i >> 3, sub = i & 7;
            int px;
            if (g < 3) px = g;
            else if (g < 3 + 2 * NROWS) {
                const int s = (g - 3) >> 1;
                px = 3 + s * RS + 56 + ((g - 3) & 1);
            } else px = 3 + NROWS * RS;
            *(f32x4*)(bufs + (size_t)px * CH + sub * 4) = z;
        }
    }

    const int wid  = t >> 6;
    const int lane = t & 63;
    const int xseg = lane >> 3;         // 8 x-strips of 7 px
    const int chq  = lane & 7;          // 8 ch-quads
    const int x0   = xseg * 7;
    const int ch   = chq * 4;
    // K=7 edge masks: window px -3/+58 land on neighbor-row data (not gap).
    const float mL = (xseg == 0) ? 0.f : 1.f;
    const float mR = (xseg == 7) ? 0.f : 1.f;

    const size_t plane = ((size_t)b * NH + hh) * (size_t)NN * CH;
    const float* vb = v + plane;

    // --- staging, split in two groups. OOB rows: num_records=0 -> zeros
    // (y zero-padding, proven R2-R4). Group 1: staged rows s<=12 (written
    // before barrier1). Group 2: s in [13, NROWS) (loads issued NOW, so
    // they are in flight across barrier1 and under conv chunk1; written
    // after chunk1).
    f32x4 ld1[4][7];
#pragma unroll
    for (int k = 0; k < 4; ++k) {
        const int s = wid + 4 * k;
        if (s <= 12) {
            const int gy = y0 - P + s;
            const bool ok = (unsigned)gy < (unsigned)HW;
            __amdgpu_buffer_rsrc_t rs = __builtin_amdgcn_make_buffer_rsrc(
                (void*)(vb + (ptrdiff_t)gy * (HW * CH)), (short)0, ok ? ROWB : 0, 0x00020000);
#pragma unroll
            for (int j = 0; j < 7; ++j) ld1[k][j] = bload(rs, j * 1024 + lane * 16);
        }
    }
    f32x4 ld2[2][7];
    const int s2b = 13 + ((wid + 3) & 3);   // smallest s>=13 with s%4==wid
#pragma unroll
    for (int k = 0; k < 2; ++k) {
        const int s = s2b + 4 * k;
        if (s < NROWS) {
            const int gy = y0 - P + s;
            const bool ok = (unsigned)gy < (unsigned)HW;
            __amdgpu_buffer_rsrc_t rs = __builtin_amdgcn_make_buffer_rsrc(
                (void*)(vb + (ptrdiff_t)gy * (HW * CH)), (short)0, ok ? ROWB : 0, 0x00020000);
#pragma unroll
            for (int j = 0; j < 7; ++j) ld2[k][j] = bload(rs, j * 1024 + lane * 16);
        }
    }
    // Write group 1 (compiler emits vmcnt(#outstanding-ld2) automatically —
    // waits for ld1 only, ld2 stays in flight).
#pragma unroll
    for (int k = 0; k < 4; ++k) {
        const int s = wid + 4 * k;
        if (s <= 12) {
            float* dst = bufs + (size_t)(3 + s * RS) * CH;
#pragma unroll
            for (int j = 0; j < 7; ++j)
                *(f32x4*)(dst + j * 256 + lane * 4) = ld1[k][j];
        }
    }
    softbar();                          // rows 0..12 + weights + pads ready

    const f32x4 bias4 = *(const f32x4*)(bias + cbase + ch);

    // chunk1: owned rows whose full window is within staged rows 0..12.
    // Wave owns rows wid, wid+4, wid+8, wid+12 (stride-4 => both chunks
    // are balanced across waves). ld2 loads fly under these FMAs.
#pragma unroll
    for (int u = 0; u < 4; ++u) {
        const int y = wid + 4 * u;
        if (y < 14 && y + 2 * P <= 12)
            conv_row<K>(q, out, bias4, b, hh, y0, y, cbase, w_lds, bufs, x0, ch, mL, mR);
    }

    // Write group 2 (vmcnt(0) here is cheap: loads issued long ago).
#pragma unroll
    for (int k = 0; k < 2; ++k) {
        const int s = s2b + 4 * k;
        if (s < NROWS) {
            float* dst = bufs + (size_t)(3 + s * RS) * CH;
#pragma unroll
            for (int j = 0; j < 7; ++j)
                *(f32x4*)(dst + j * 256 + lane * 4) = ld2[k][j];
        }
    }
    softbar();                          // rows 13..NROWS-1 ready

    // chunk2: remaining rows; epilogue stores of chunk1 rows already
    // retired, these overlap other waves' tails.
#pragma unroll
    for (int u = 0; u < 4; ++u) {
        const int y = wid + 4 * u;
        if (y < 14 && y + 2 * P > 12)
            conv_row<K>(q, out, bias4, b, hh, y0, y, cbase, w_lds, bufs, x0, ch, mL, mR);
    }
}

__global__ __launch_bounds__(256, 1)   // 155.3 KB LDS -> 1 block/CU
void clusterformer_fused(const float* __restrict__ q, const float* __restrict__ v,
                         const float* __restrict__ w3, const float* __restrict__ b3,
                         const float* __restrict__ w5, const float* __restrict__ b5,
                         const float* __restrict__ w7, const float* __restrict__ b7,
                         float* __restrict__ out)
{
    __shared__ __align__(16) float bufs[BUF_FLOATS];   // 148992 B
    __shared__ __align__(16) float w_lds[49 * CH];     // 6272 B

    // bid -> (plane p, ygroup): XCD-local planes, heavy heads (K7) first;
    // this decode pairs heavy+light blocks per CU across the two rounds
    // (R9 ordering — best FETCH of the series).
    const int bid  = blockIdx.x;
    const int p_lo = bid & 7;
    const int t2   = bid >> 3;         // 0..63
    const int p_hi = t2 >> 2;          // 0..15
    const int yg   = t2 & 3;           // 0..3
    const int p    = p_hi * 8 + p_lo;  // 0..127
    const int b    = p & 15;
    const int hhp  = p >> 4;           // dispatch-ordered head
    const int hh   = (hhp < 3) ? (5 + hhp) : ((hhp < 6) ? (hhp - 1) : (hhp - 6));
    const int y0   = yg * 14;

    if (hh < 2)      run_head<3>(q, v, w3, b3, out, b, hh, y0, hh * 32,       w_lds, bufs);
    else if (hh < 5) run_head<5>(q, v, w5, b5, out, b, hh, y0, hh * 32 - 64,  w_lds, bufs);
    else             run_head<7>(q, v, w7, b7, out, b, hh, y0, hh * 32 - 160, w_lds, bufs);
}

extern "C" void kernel_launch(void* const* d_in, const int* in_sizes, int n_in,
                              void* d_out, int out_size, void* d_ws, size_t ws_size,
                              hipStream_t stream) {
    const float* q  = (const float*)d_in[0];
    const float* v  = (const float*)d_in[1];
    const float* w3 = (const float*)d_in[2];
    const float* b3 = (const float*)d_in[3];
    const float* w5 = (const float*)d_in[4];
    const float* b5 = (const float*)d_in[5];
    const float* w7 = (const float*)d_in[6];
    const float* b7 = (const float*)d_in[7];
    float* out = (float*)d_out;

    const int grid = BH * NH * 4;      // 512 blocks of 256 threads
    clusterformer_fused<<<grid, 256, 0, stream>>>(q, v, w3, b3, w5, b5, w7, b7, out);
}